// Round 1
// baseline (826.475 us; speedup 1.0000x reference)
//
#include <hip/hip_runtime.h>
#include <cmath>

#define BATCH 1024

// ---------------- Level 0: diva0, r0, base us0 ----------------
__global__ __launch_bounds__(256) void k_level0(
    const float* __restrict__ u, const float* __restrict__ f, const float* __restrict__ a,
    const float* __restrict__ c0w, const float* __restrict__ c0b,
    const float* __restrict__ c1w, const float* __restrict__ c1b,
    float* __restrict__ out_us0, float* __restrict__ out_diva0, float* __restrict__ ws_r0)
{
    const int b = blockIdx.z;
    const int y0 = blockIdx.y * 16, x0 = blockIdx.x * 16;
    const int tx = threadIdx.x & 15, ty = threadIdx.x >> 4;
    __shared__ float a_s[19][20];   // a tile, origin (y0-1, x0-1)
    __shared__ float td[18][19];    // tanh(diva), origin (y0-1, x0-1)

    const float* ab = a + (size_t)b * 16384;
    for (int idx = threadIdx.x; idx < 19 * 19; idx += 256) {
        int r = idx / 19, c = idx % 19;
        int gy = y0 - 1 + r; gy = gy < 0 ? 0 : (gy > 127 ? 127 : gy);
        int gx = x0 - 1 + c; gx = gx < 0 ? 0 : (gx > 127 ? 127 : gx);
        a_s[r][c] = ab[gy * 128 + gx];
    }
    __syncthreads();
    const float w00 = c1w[0], w01 = c1w[1], w10 = c1w[2], w11 = c1w[3];
    const float b1 = c1b[0];
    for (int idx = threadIdx.x; idx < 18 * 18; idx += 256) {
        int r = idx / 18, c = idx % 18;
        int dy = y0 - 1 + r, dx = x0 - 1 + c;
        if (dy >= 0 && dy <= 126 && dx >= 0 && dx <= 126) {
            float d = a_s[r][c] * w00 + a_s[r][c + 1] * w01
                    + a_s[r + 1][c] * w10 + a_s[r + 1][c + 1] * w11 + b1;
            td[r][c] = tanhf(d);
        }
    }
    __syncthreads();
    const int y = y0 + ty, x = x0 + tx;
    if (y < 127 && x < 127) {
        float diva = a_s[ty + 1][tx + 1] * w00 + a_s[ty + 1][tx + 2] * w01
                   + a_s[ty + 2][tx + 1] * w10 + a_s[ty + 2][tx + 2] * w11 + b1;
        size_t idx = (size_t)b * 16129 + (size_t)y * 127 + x;
        float uv = u[idx], fv = f[idx];
        float rv = fv - diva * uv;
        float s = c0b[0];
        #pragma unroll
        for (int ky = 0; ky < 3; ky++) {
            int sy = y - 1 + ky; sy = sy < 0 ? 0 : (sy > 126 ? 126 : sy);
            int lr = sy - (y0 - 1);
            #pragma unroll
            for (int kx = 0; kx < 3; kx++) {
                int sx = x - 1 + kx; sx = sx < 0 ? 0 : (sx > 126 ? 126 : sx);
                s += c0w[ky * 3 + kx] * td[lr][sx - (x0 - 1)];
            }
        }
        out_diva0[idx] = diva;
        ws_r0[idx] = rv;
        out_us0[idx] = uv + s * rv;
    }
}

// ---------------- Levels 1..4: restrict a,r + Conv_Dyn ----------------
__global__ __launch_bounds__(256) void k_restrict(
    const float* __restrict__ a_prev, const float* __restrict__ r_prev,
    float* __restrict__ a_out, float* __restrict__ r_out,
    float* __restrict__ us_out, float* __restrict__ diva_out,
    const float* __restrict__ r1w, const float* __restrict__ r3w,
    const float* __restrict__ c1w, const float* __restrict__ c1b,
    const float* __restrict__ c0w, const float* __restrict__ c0b,
    int n, int na)  // n = diva/r/u size, na = n+1 (a size); prev a = 2*na, prev r = 2*n+1
{
    const int b = blockIdx.z;
    const int y0 = blockIdx.y * 16, x0 = blockIdx.x * 16;
    const int tx = threadIdx.x & 15, ty = threadIdx.x >> 4;
    const int npa = 2 * na, npd = 2 * n + 1;
    __shared__ float a_s[19][20];
    __shared__ float td[18][19];
    const float* apb = a_prev + (size_t)b * npa * npa;
    const float* rpb = r_prev + (size_t)b * npd * npd;
    const float q00 = r1w[0], q01 = r1w[1], q10 = r1w[2], q11 = r1w[3];
    // a_i tile (restricted), origin (y0-1, x0-1), clamped coords
    for (int idx = threadIdx.x; idx < 19 * 19; idx += 256) {
        int r = idx / 19, c = idx % 19;
        int ay = y0 - 1 + r; ay = ay < 0 ? 0 : (ay > na - 1 ? na - 1 : ay);
        int ax = x0 - 1 + c; ax = ax < 0 ? 0 : (ax > na - 1 ? na - 1 : ax);
        const float* p = apb + (size_t)(2 * ay) * npa + 2 * ax;
        a_s[r][c] = p[0] * q00 + p[1] * q01 + p[npa] * q10 + p[npa + 1] * q11;
    }
    __syncthreads();
    const float w00 = c1w[0], w01 = c1w[1], w10 = c1w[2], w11 = c1w[3], b1 = c1b[0];
    for (int idx = threadIdx.x; idx < 18 * 18; idx += 256) {
        int r = idx / 18, c = idx % 18;
        int dy = y0 - 1 + r, dx = x0 - 1 + c;
        if (dy >= 0 && dy < n && dx >= 0 && dx < n) {
            float d = a_s[r][c] * w00 + a_s[r][c + 1] * w01
                    + a_s[r + 1][c] * w10 + a_s[r + 1][c + 1] * w11 + b1;
            td[r][c] = tanhf(d);
        }
    }
    __syncthreads();
    const int y = y0 + ty, x = x0 + tx;
    if (y < na && x < na)
        a_out[(size_t)b * na * na + (size_t)y * na + x] = a_s[ty + 1][tx + 1];
    if (y < n && x < n) {
        float diva = a_s[ty + 1][tx + 1] * w00 + a_s[ty + 1][tx + 2] * w01
                   + a_s[ty + 2][tx + 1] * w10 + a_s[ty + 2][tx + 2] * w11 + b1;
        float rv = 0.f;
        #pragma unroll
        for (int p = 0; p < 3; p++)
            #pragma unroll
            for (int q = 0; q < 3; q++)
                rv += r3w[p * 3 + q] * rpb[(size_t)(2 * y + p) * npd + 2 * x + q];
        float s = c0b[0];
        #pragma unroll
        for (int ky = 0; ky < 3; ky++) {
            int sy = y - 1 + ky; sy = sy < 0 ? 0 : (sy > n - 1 ? n - 1 : sy);
            int lr = sy - (y0 - 1);
            #pragma unroll
            for (int kx = 0; kx < 3; kx++) {
                int sx = x - 1 + kx; sx = sx < 0 ? 0 : (sx > n - 1 ? n - 1 : sx);
                s += c0w[ky * 3 + kx] * td[lr][sx - (x0 - 1)];
            }
        }
        size_t idx = (size_t)b * n * n + (size_t)y * n + x;
        diva_out[idx] = diva;
        r_out[idx] = rv;
        us_out[idx] = s * rv;
    }
}

// ---------------- Prolongation: us_out += convT3 s2 (us_in) ----------------
__global__ __launch_bounds__(256) void k_prolong(
    float* __restrict__ us_out, const float* __restrict__ us_in,
    const float* __restrict__ tw, int n_out, int n_in)
{
    const int b = blockIdx.z;
    const int y = blockIdx.y * 16 + (threadIdx.x >> 4);
    const int x = blockIdx.x * 16 + (threadIdx.x & 15);
    if (y >= n_out || x >= n_out) return;
    const float* ib = us_in + (size_t)b * n_in * n_in;
    float acc = 0.f;
    #pragma unroll
    for (int ky = 0; ky < 3; ky++) {
        int sy = y - ky;
        if (sy & 1) continue;
        int iy = sy >> 1;
        if (iy < 0 || iy >= n_in) continue;
        #pragma unroll
        for (int kx = 0; kx < 3; kx++) {
            int sx = x - kx;
            if (sx & 1) continue;
            int ix = sx >> 1;
            if (ix < 0 || ix >= n_in) continue;
            acc += tw[ky * 3 + kx] * ib[(size_t)iy * n_in + ix];
        }
    }
    size_t idx = (size_t)b * n_out * n_out + (size_t)y * n_out + x;
    us_out[idx] += acc;
}

extern "C" void kernel_launch(void* const* d_in, const int* in_sizes, int n_in,
                              void* d_out, int out_size, void* d_ws, size_t ws_size,
                              hipStream_t stream) {
    const float* u   = (const float*)d_in[0];
    const float* f   = (const float*)d_in[1];
    const float* a   = (const float*)d_in[2];
    const float* c0w = (const float*)d_in[3];
    const float* c0b = (const float*)d_in[4];
    const float* c1w = (const float*)d_in[5];
    const float* c1b = (const float*)d_in[6];
    const float* r1w = (const float*)d_in[7];
    const float* r3w = (const float*)d_in[8];
    const float* tw  = (const float*)d_in[9];
    float* out = (float*)d_out;
    float* ws  = (float*)d_ws;
    const size_t B = BATCH;

    static const int HD[5] = {127, 63, 31, 15, 7};   // diva/r/u sizes
    static const int HA[5] = {128, 64, 32, 16, 8};   // a sizes

    // d_out layout: us0, f, a, diva0..diva4
    size_t off_us0 = 0;
    size_t off_f   = B * 16129;
    size_t off_a   = off_f + B * 16129;
    size_t off_diva[5];
    off_diva[0] = off_a + B * 16384;
    off_diva[1] = off_diva[0] + B * 16129;
    off_diva[2] = off_diva[1] + B * 3969;
    off_diva[3] = off_diva[2] + B * 961;
    off_diva[4] = off_diva[3] + B * 225;

    // ws layout: r0, then per level i=1..4: a_i, r_i, us_i
    size_t w_r0 = 0;
    size_t w_a[5], w_r[5], w_us[5];
    size_t cur = w_r0 + B * 16129;
    for (int i = 1; i < 5; i++) {
        w_a[i]  = cur; cur += B * (size_t)(HA[i] * HA[i]);
        w_r[i]  = cur; cur += B * (size_t)(HD[i] * HD[i]);
        w_us[i] = cur; cur += B * (size_t)(HD[i] * HD[i]);
    }

    // passthrough outputs
    hipMemcpyAsync(out + off_f, f, B * 16129 * sizeof(float), hipMemcpyDeviceToDevice, stream);
    hipMemcpyAsync(out + off_a, a, B * 16384 * sizeof(float), hipMemcpyDeviceToDevice, stream);

    dim3 blk(256);
    k_level0<<<dim3(8, 8, B), blk, 0, stream>>>(
        u, f, a, c0w, c0b, c1w, c1b, out + off_us0, out + off_diva[0], ws + w_r0);

    for (int i = 1; i < 5; i++) {
        int n = HD[i], na = HA[i];
        int g = (na + 15) / 16;
        const float* a_prev = (i == 1) ? a : ws + w_a[i - 1];
        const float* r_prev = (i == 1) ? ws + w_r0 : ws + w_r[i - 1];
        k_restrict<<<dim3(g, g, B), blk, 0, stream>>>(
            a_prev, r_prev, ws + w_a[i], ws + w_r[i], ws + w_us[i], out + off_diva[i],
            r1w + (size_t)(i - 1) * 4, r3w + (size_t)(i - 1) * 9,
            c1w + (size_t)i * 4, c1b + i, c0w + (size_t)i * 9, c0b + i, n, na);
    }

    for (int i = 3; i >= 0; i--) {
        int no = HD[i], ni = HD[i + 1];
        int g = (no + 15) / 16;
        float* us_dst = (i == 0) ? (out + off_us0) : (ws + w_us[i]);
        k_prolong<<<dim3(g, g, B), blk, 0, stream>>>(
            us_dst, ws + w_us[i + 1], tw + (size_t)i * 9, no, ni);
    }
}